// Round 8
// baseline (1997.307 us; speedup 1.0000x reference)
//
#include <hip/hip_runtime.h>
#include <hip/hip_bf16.h>
#include <cstddef>

// ---------------------------------------------------------------------------
// EncoderModule: 5x causal conv1d (K=7) + ELU, then 2x VQ argmin (1024 codes, D=64)
// B=64, L=48000, strides 2,2,2,3,1; channels 1->16->32->64->64->128
// Output: int32 indices, shape (2, 64, 2000)
//
// conv0-3: fp32 VALU (conv_wave: lane=t, wave-uniform co -> s_load weights).
// conv4:   split-bf16 MFMA GEMM (7 shifted K=64 GEMMs, hi/lo split, |dz|<~6e-4).
// VQ:      split-bf16 MFMA scores; gap < 0.25 -> flag; rescore recomputes z
//          EXACTLY in fp32 from h3 and rescans all 1024 codes.
// ---------------------------------------------------------------------------

using bf16x8 = __attribute__((ext_vector_type(8))) short;
using f32x4  = __attribute__((ext_vector_type(4))) float;

static __device__ __forceinline__ short f2bf(float f) {
    __hip_bfloat16 h = __float2bfloat16(f);   // RNE
    union { __hip_bfloat16 h; short s; } u; u.h = h;
    return u.s;
}
static __device__ __forceinline__ float bf2f(short s) {
    union { unsigned u; float f; } v;
    v.u = ((unsigned)(unsigned short)s) << 16;
    return v.f;
}

// ---------------- conv_wave (round-6 verified): convs 0-3 -------------------
template<int CIN, int S, int CO_T, int TT>
__global__ __launch_bounds__(256) void conv_wave_kernel(
    const float* __restrict__ x, const float* __restrict__ w,
    const float* __restrict__ bias, float* __restrict__ y,
    int B, int Lin, int Lout, int Cout)
{
    constexpr int NT   = 64 * TT;
    constexpr int XLEN = (NT - 1) * S + 7;
    __shared__ float xs[CIN][XLEN];

    int tb  = blockIdx.x;
    int cbk = blockIdx.y;
    int b   = blockIdx.z;
    int t0  = tb * NT;
    int tid  = threadIdx.x;
    int lane = tid & 63;
    int wv   = __builtin_amdgcn_readfirstlane(tid >> 6);

    const float* xb = x + (size_t)b * CIN * Lin;
    int g0 = t0 * S - 6;
    for (int i = tid; i < CIN * XLEN; i += 256) {
        int ci = i / XLEN, xo = i % XLEN;
        int gx = g0 + xo;
        xs[ci][xo] = (gx >= 0 && gx < Lin) ? xb[(size_t)ci * Lin + gx] : 0.0f;
    }
    __syncthreads();

    int co0 = cbk * (4 * CO_T) + wv * CO_T;
    const float* wbase = w + (size_t)co0 * CIN * 7;

    float acc[CO_T][TT];
    #pragma unroll
    for (int c = 0; c < CO_T; ++c)
        #pragma unroll
        for (int u = 0; u < TT; ++u) acc[c][u] = 0.0f;

    for (int ci = 0; ci < CIN; ++ci) {
        float xw[TT][7];
        #pragma unroll
        for (int u = 0; u < TT; ++u)
            #pragma unroll
            for (int k = 0; k < 7; ++k)
                xw[u][k] = xs[ci][(lane + 64 * u) * S + k];
        #pragma unroll
        for (int c = 0; c < CO_T; ++c) {
            const float* wp = wbase + (size_t)c * CIN * 7 + ci * 7;  // s_load
            #pragma unroll
            for (int k = 0; k < 7; ++k) {
                float wk = wp[k];
                #pragma unroll
                for (int u = 0; u < TT; ++u)
                    acc[c][u] = fmaf(wk, xw[u][k], acc[c][u]);
            }
        }
    }

    #pragma unroll
    for (int u = 0; u < TT; ++u) {
        int t = t0 + lane + 64 * u;
        if (t < Lout) {
            #pragma unroll
            for (int c = 0; c < CO_T; ++c) {
                float v = acc[c][u] + bias[co0 + c];
                y[((size_t)b * Cout + co0 + c) * Lout + t] = v > 0.0f ? v : expm1f(v);
            }
        }
    }
}

// ---------------- conv4 weight prep: hi/lo bf16 A-fragments -----------------
// A element for 16x16x32: (m = mt*16 + (lane&15), k = kc*32 + (lane>>4)*8 + j)
// frag addr: (((mt*2+kc)*7+k_shift)*2+hl)*512 + lane*8   (shorts)
__global__ __launch_bounds__(128) void wprep_kernel(
    const float* __restrict__ wq, short* __restrict__ wfrag)
{
    int co = threadIdx.x;            // 0..127
    int mt = co >> 4, nc = co & 15;
    #pragma unroll
    for (int kc = 0; kc < 2; ++kc)
        for (int k = 0; k < 7; ++k)
            #pragma unroll
            for (int lh = 0; lh < 4; ++lh) {
                bf16x8 ph, pl;
                #pragma unroll
                for (int j = 0; j < 8; ++j) {
                    int ci = kc * 32 + lh * 8 + j;
                    float f = wq[(size_t)co * 448 + ci * 7 + k];
                    short h = f2bf(f);
                    ph[j] = h;
                    pl[j] = f2bf(f - bf2f(h));
                }
                size_t base = (((size_t)mt * 2 + kc) * 7 + k) * 2;
                *(bf16x8*)(wfrag + (base + 0) * 512 + (lh * 16 + nc) * 8) = ph;
                *(bf16x8*)(wfrag + (base + 1) * 512 + (lh * 16 + nc) * 8) = pl;
            }
}

// ---------------- conv4: split-bf16 MFMA GEMM over 7 shifts -----------------
#define C4_T 2000
__global__ __launch_bounds__(256) void conv4_mfma_kernel(
    const float* __restrict__ h3, const short* __restrict__ wfrag,
    const float* __restrict__ bq, float* __restrict__ z)
{
    constexpr int NT = 128, ROWS = NT + 6;
    __shared__ short ht0[ROWS * 64];   // hi plane, XOR-swizzled rows of 128 B
    __shared__ short ht1[ROWS * 64];   // lo plane

    int nb = blockIdx.x;               // 16 n-blocks of 128 t
    int b  = blockIdx.y;
    int t0 = nb * NT;
    int tid = threadIdx.x, lane = tid & 63, wv = tid >> 6;

    const float* hb = h3 + (size_t)b * 64 * C4_T;
    for (int e = tid; e < 64 * ROWS; e += 256) {
        int ci = e / ROWS, tt = e % ROWS;
        int t = t0 - 6 + tt;
        float v = (t >= 0 && t < C4_T) ? hb[(size_t)ci * C4_T + t] : 0.0f;
        short h = f2bf(v);
        short l = f2bf(v - bf2f(h));
        int byte = tt * 128 + ((ci * 2) ^ ((tt & 7) << 4));
        *(short*)((char*)ht0 + byte) = h;
        *(short*)((char*)ht1 + byte) = l;
    }
    __syncthreads();

    f32x4 acc[2][8];
    #pragma unroll
    for (int n = 0; n < 2; ++n)
        #pragma unroll
        for (int m = 0; m < 8; ++m) acc[n][m] = (f32x4){0.f, 0.f, 0.f, 0.f};

    int ncol = lane & 15, nq = lane >> 4;

    for (int k = 0; k < 7; ++k) {
        #pragma unroll
        for (int kc = 0; kc < 2; ++kc) {
            int colb = (kc * 32 + nq * 8) * 2;
            bf16x8 Bh[2], Bl[2];
            #pragma unroll
            for (int ntl = 0; ntl < 2; ++ntl) {
                int r = (2 * wv + ntl) * 16 + ncol + k;
                int byte = r * 128 + (colb ^ ((r & 7) << 4));
                Bh[ntl] = *(const bf16x8*)((const char*)ht0 + byte);
                Bl[ntl] = *(const bf16x8*)((const char*)ht1 + byte);
            }
            #pragma unroll
            for (int m = 0; m < 8; ++m) {
                size_t base = (((size_t)m * 2 + kc) * 7 + k) * 2;
                bf16x8 ah = *(const bf16x8*)(wfrag + (base + 0) * 512 + lane * 8);
                bf16x8 al = *(const bf16x8*)(wfrag + (base + 1) * 512 + lane * 8);
                #pragma unroll
                for (int ntl = 0; ntl < 2; ++ntl) {
                    acc[ntl][m] = __builtin_amdgcn_mfma_f32_16x16x32_bf16(ah, Bh[ntl], acc[ntl][m], 0, 0, 0);
                    acc[ntl][m] = __builtin_amdgcn_mfma_f32_16x16x32_bf16(ah, Bl[ntl], acc[ntl][m], 0, 0, 0);
                    acc[ntl][m] = __builtin_amdgcn_mfma_f32_16x16x32_bf16(al, Bh[ntl], acc[ntl][m], 0, 0, 0);
                }
            }
        }
    }

    #pragma unroll
    for (int ntl = 0; ntl < 2; ++ntl) {
        int n = t0 + (2 * wv + ntl) * 16 + ncol;
        if (n < C4_T) {
            #pragma unroll
            for (int m = 0; m < 8; ++m) {
                #pragma unroll
                for (int j = 0; j < 4; ++j) {
                    int co = m * 16 + nq * 4 + j;
                    float v = acc[ntl][m][j] + bq[co];
                    v = v > 0.0f ? v : expm1f(v);
                    z[((size_t)b * 128 + co) * C4_T + n] = v;
                }
            }
        }
    }
}

// ---------------- VQ prep: cc (fp32) + codebook hi/lo bf16 B-fragments ------
__global__ __launch_bounds__(256) void vq_prep_kernel(
    const float* __restrict__ cbs, float* __restrict__ cc, short* __restrict__ cbf)
{
    int c = blockIdx.x * 256 + threadIdx.x;   // 0..2047
    if (c >= 2048) return;
    int cb = c >> 10, nl = c & 1023;
    const float* row = cbs + (size_t)c * 64;
    float v[64];
    float s = 0.f;
    #pragma unroll
    for (int i = 0; i < 16; ++i) {
        float4 q = ((const float4*)row)[i];
        v[4*i+0] = q.x; v[4*i+1] = q.y; v[4*i+2] = q.z; v[4*i+3] = q.w;
        s += q.x*q.x + q.y*q.y + q.z*q.z + q.w*q.w;
    }
    cc[c] = s;
    int nt = nl >> 4, nc = nl & 15;
    #pragma unroll
    for (int kc = 0; kc < 2; ++kc)
        #pragma unroll
        for (int lh = 0; lh < 4; ++lh) {
            bf16x8 ph, pl;
            #pragma unroll
            for (int j = 0; j < 8; ++j) {
                float f = v[kc*32 + lh*8 + j];
                short h = f2bf(f);
                ph[j] = h;
                pl[j] = f2bf(f - bf2f(h));
            }
            size_t base = ((((size_t)cb*64 + nt)*2 + kc)*2);
            *(bf16x8*)(cbf + ((base + 0)*64 + (lh*16 + nc)) * 8) = ph;
            *(bf16x8*)(cbf + ((base + 1)*64 + (lh*16 + nc)) * 8) = pl;
        }
}

__global__ void zero_cnt_kernel(int* cnt) {
    if (threadIdx.x == 0 && blockIdx.x == 0) *cnt = 0;
}

// ---------------- VQ main: split-bf16 MFMA + best/second + flag -------------
// margin covers: VQ bf16-split err (~0.004) + conv4 bf16-split z-shift
// (paranoid bound ~0.077). 0.25 > 2*(sum) with >1.5x slack.
#define VQ_MARGIN 0.25f

__global__ __launch_bounds__(256) void vq_mfma_kernel(
    const float* __restrict__ z, const short* __restrict__ cbf,
    const float* __restrict__ ccg, int* __restrict__ out,
    int* __restrict__ cnt, int* __restrict__ list)
{
    __shared__ short zf[2][8*2*64*8];     // 32 KB: A-frags [hl][mt(8)][kc(2)][lane][j]
    __shared__ short cbc[8*2*2*64*8];     // 32 KB: B-frag chunk (128 codes, hi+lo)
    __shared__ float ccl[128];

    const int T = 2000;
    int mblk = blockIdx.x;   // 16 m-blocks of 128 t
    int cb   = blockIdx.y;
    int b    = blockIdx.z;
    int t0   = mblk * 128;
    int tid  = threadIdx.x;
    int lane = tid & 63;
    int wv   = tid >> 6;

    const float* zb = z + ((size_t)b*128 + (size_t)cb*64) * T;
    bool tail = (t0 + 128 > T);
    #pragma unroll
    for (int p = 0; p < 8; ++p) {
        int d    = p*8 + (tid >> 5);
        int toff = (tid & 31) * 4;
        float qa[4];
        if (!tail) {
            float4 q = *(const float4*)(zb + (size_t)d*T + t0 + toff);
            qa[0]=q.x; qa[1]=q.y; qa[2]=q.z; qa[3]=q.w;
        } else {
            #pragma unroll
            for (int u = 0; u < 4; ++u) {
                int tt = t0 + toff + u; if (tt > T-1) tt = T-1;
                qa[u] = zb[(size_t)d*T + tt];
            }
        }
        #pragma unroll
        for (int u = 0; u < 4; ++u) {
            int tl = toff + u;
            int mt = tl >> 4;
            int lw = ((d & 31) >> 3) * 16 + (tl & 15);
            int kc = d >> 5;
            int idx = (((mt*2 + kc)*64) + lw)*8 + (d & 7);
            short h = f2bf(qa[u]);
            zf[0][idx] = h;
            zf[1][idx] = f2bf(qa[u] - bf2f(h));
        }
    }
    __syncthreads();

    bf16x8 ah[2][2], al[2][2];
    #pragma unroll
    for (int mtl = 0; mtl < 2; ++mtl)
        #pragma unroll
        for (int kc = 0; kc < 2; ++kc) {
            int idx = ((((wv*2+mtl)*2 + kc)*64) + lane)*8;
            ah[mtl][kc] = *(const bf16x8*)&zf[0][idx];
            al[mtl][kc] = *(const bf16x8*)&zf[1][idx];
        }

    float best[2][4], second[2][4]; int bidx[2][4];
    #pragma unroll
    for (int m = 0; m < 2; ++m)
        #pragma unroll
        for (int j = 0; j < 4; ++j) { best[m][j] = 3.4e38f; second[m][j] = 3.4e38f; bidx[m][j] = 0; }

    const short* cbase = cbf + (size_t)cb * (64*2*2*64*8);
    const float* ccb   = ccg + cb * 1024;

    for (int ch = 0; ch < 8; ++ch) {
        __syncthreads();
        {
            const float4* src = (const float4*)(cbase + (size_t)ch * (8*2*2*64*8));
            float4* dst = (float4*)cbc;
            #pragma unroll
            for (int i = 0; i < 8; ++i) dst[tid + 256*i] = src[tid + 256*i];
            if (tid < 128) ccl[tid] = ccb[ch*128 + tid];
        }
        __syncthreads();

        for (int ntl = 0; ntl < 8; ++ntl) {
            bf16x8 b0h = *(const bf16x8*)&cbc[(((ntl*2 + 0)*2 + 0)*64 + lane)*8];
            bf16x8 b0l = *(const bf16x8*)&cbc[(((ntl*2 + 0)*2 + 1)*64 + lane)*8];
            bf16x8 b1h = *(const bf16x8*)&cbc[(((ntl*2 + 1)*2 + 0)*64 + lane)*8];
            bf16x8 b1l = *(const bf16x8*)&cbc[(((ntl*2 + 1)*2 + 1)*64 + lane)*8];
            float ccv = ccl[ntl*16 + (lane & 15)];
            int  code = ch*128 + ntl*16 + (lane & 15);
            #pragma unroll
            for (int mtl = 0; mtl < 2; ++mtl) {
                f32x4 p = {0.f,0.f,0.f,0.f}, q = {0.f,0.f,0.f,0.f};
                p = __builtin_amdgcn_mfma_f32_16x16x32_bf16(ah[mtl][0], b0h, p, 0, 0, 0);
                q = __builtin_amdgcn_mfma_f32_16x16x32_bf16(ah[mtl][1], b1h, q, 0, 0, 0);
                p = __builtin_amdgcn_mfma_f32_16x16x32_bf16(ah[mtl][0], b0l, p, 0, 0, 0);
                q = __builtin_amdgcn_mfma_f32_16x16x32_bf16(ah[mtl][1], b1l, q, 0, 0, 0);
                p = __builtin_amdgcn_mfma_f32_16x16x32_bf16(al[mtl][0], b0h, p, 0, 0, 0);
                q = __builtin_amdgcn_mfma_f32_16x16x32_bf16(al[mtl][1], b1h, q, 0, 0, 0);
                #pragma unroll
                for (int j = 0; j < 4; ++j) {
                    float s = fmaf(-2.0f, p[j] + q[j], ccv);
                    bool lt = s < best[mtl][j];
                    second[mtl][j] = fminf(second[mtl][j], fmaxf(best[mtl][j], s));
                    best[mtl][j]   = fminf(best[mtl][j], s);
                    bidx[mtl][j]   = lt ? code : bidx[mtl][j];
                }
            }
        }
    }

    #pragma unroll
    for (int m = 0; m < 2; ++m)
        #pragma unroll
        for (int j = 0; j < 4; ++j) {
            float bv = best[m][j], sv = second[m][j]; int bi = bidx[m][j];
            #pragma unroll
            for (int d = 1; d < 16; d <<= 1) {
                float ob = __shfl_xor(bv, d, 64);
                float os = __shfl_xor(sv, d, 64);
                int   oi = __shfl_xor(bi, d, 64);
                float loser = fmaxf(bv, ob);
                sv = fminf(fminf(sv, os), loser);
                bool sw = ob < bv;
                bv = fminf(bv, ob);
                bi = sw ? oi : bi;
            }
            if ((lane & 15) == 0) {
                int t = t0 + (wv*2 + m)*16 + (lane >> 4)*4 + j;
                if (t < T) {
                    out[((size_t)cb*64 + b)*T + t] = bi;
                    if (sv - bv < VQ_MARGIN) {
                        int pos = atomicAdd(cnt, 1);
                        list[pos] = (cb << 17) | (b << 11) | t;
                    }
                }
            }
        }
}

// ---------------- VQ rescore: exact fp32 (conv4 recompute + full scan) ------
__global__ __launch_bounds__(256) void vq_rescore_kernel(
    const float* __restrict__ h3, const float* __restrict__ wq,
    const float* __restrict__ bq, const float* __restrict__ cbs,
    const float* __restrict__ ccg, const int* __restrict__ cnt,
    const int* __restrict__ list, int* __restrict__ out)
{
    const int T = 2000;
    int lane = threadIdx.x & 63;
    int gw = (blockIdx.x * 256 + threadIdx.x) >> 6;
    int count = *cnt;

    for (int i = gw; i < count; i += 1024) {
        int e = list[i];
        int cb = e >> 17, b = (e >> 11) & 63, t = e & 2047;

        // exact fp32 conv4 for dim d = cb*64 + lane
        int d = cb * 64 + lane;
        const float* wrow = wq + (size_t)d * 448;
        const float* hb   = h3 + (size_t)b * 64 * T;
        float a0 = 0.f, a1 = 0.f, a2 = 0.f, a3 = 0.f;
        if (t >= 6) {
            for (int ci = 0; ci < 64; ++ci) {
                const float* hp = hb + (size_t)ci * T + t - 6;
                const float* wp = wrow + ci * 7;
                a0 = fmaf(wp[0], hp[0], a0);
                a1 = fmaf(wp[1], hp[1], a1);
                a2 = fmaf(wp[2], hp[2], a2);
                a3 = fmaf(wp[3], hp[3], a3);
                a0 = fmaf(wp[4], hp[4], a0);
                a1 = fmaf(wp[5], hp[5], a1);
                a2 = fmaf(wp[6], hp[6], a2);
            }
        } else {
            for (int ci = 0; ci < 64; ++ci)
                for (int k = 6 - t; k < 7; ++k)
                    a0 = fmaf(wrow[ci*7 + k], hb[(size_t)ci * T + t - 6 + k], a0);
        }
        float zd = (a0 + a1) + (a2 + a3) + bq[d];
        zd = zd > 0.0f ? zd : expm1f(zd);

        // broadcast z row to all lanes
        float zr[64];
        #pragma unroll
        for (int j = 0; j < 64; ++j) zr[j] = __shfl(zd, j, 64);

        const float* cbase = cbs + (size_t)cb * 1024 * 64;
        const float* ccb   = ccg + cb * 1024;
        float bv = 3.4e38f; int bi = 0x7fffffff;
        for (int ii = 0; ii < 16; ++ii) {
            int code = ii*64 + lane;
            const float4* cp = (const float4*)(cbase + (size_t)code * 64);
            float d0 = 0.f, d1 = 0.f, d2 = 0.f, d3 = 0.f;
            #pragma unroll
            for (int q = 0; q < 16; ++q) {
                float4 cv = cp[q];
                d0 = fmaf(zr[4*q+0], cv.x, d0);
                d1 = fmaf(zr[4*q+1], cv.y, d1);
                d2 = fmaf(zr[4*q+2], cv.z, d2);
                d3 = fmaf(zr[4*q+3], cv.w, d3);
            }
            float s = fmaf(-2.0f, (d0 + d1) + (d2 + d3), ccb[code]);
            if (s < bv) { bv = s; bi = code; }
        }
        #pragma unroll
        for (int dd = 1; dd < 64; dd <<= 1) {
            float ov = __shfl_xor(bv, dd, 64);
            int   oi = __shfl_xor(bi, dd, 64);
            if (ov < bv || (ov == bv && oi < bi)) { bv = ov; bi = oi; }
        }
        if (lane == 0) out[((size_t)cb*64 + b)*T + t] = bi;
    }
}

extern "C" void kernel_launch(void* const* d_in, const int* in_sizes, int n_in,
                              void* d_out, int out_size, void* d_ws, size_t ws_size,
                              hipStream_t stream)
{
    const float* x   = (const float*)d_in[0];
    const float* w0  = (const float*)d_in[1];
    const float* b0  = (const float*)d_in[2];
    const float* w1  = (const float*)d_in[3];
    const float* b1  = (const float*)d_in[4];
    const float* w2  = (const float*)d_in[5];
    const float* b2  = (const float*)d_in[6];
    const float* w3  = (const float*)d_in[7];
    const float* b3  = (const float*)d_in[8];
    const float* wq  = (const float*)d_in[9];
    const float* bq  = (const float*)d_in[10];
    const float* cbs = (const float*)d_in[11];
    int* out = (int*)d_out;

    constexpr int B = 64;
    constexpr size_t BUF = 24576000;
    float* bufA = (float*)d_ws;
    float* bufB = bufA + BUF;
    // prep area: bufB + 16M floats — free after conv2 consumes h2; beyond
    // conv3's h3 (8.192M floats at bufB[0..)).
    float* prep  = bufB + 16000000;
    short* cbf   = (short*)prep;                 // 262144 shorts (VQ B-frags)
    float* cc    = prep + 131072;                // 2048 f32
    int*   cnt   = (int*)(cc + 2048);
    int*   list  = cnt + 4;                      // up to 256K ints
    short* wfrag = (short*)(prep + 400000);      // 114688 shorts (conv4 A-frags)

    // conv0: (B,1,48000) -> (B,16,24000)
    conv_wave_kernel<1, 2, 4, 2><<<dim3(188, 1, B), 256, 0, stream>>>(
        x, w0, b0, bufA, B, 48000, 24000, 16);
    // conv1: (B,16,24000) -> (B,32,12000)
    conv_wave_kernel<16, 2, 8, 2><<<dim3(94, 1, B), 256, 0, stream>>>(
        bufA, w1, b1, bufB, B, 24000, 12000, 32);
    // conv2: (B,32,12000) -> (B,64,6000)  CO_T=16
    conv_wave_kernel<32, 2, 16, 2><<<dim3(47, 1, B), 256, 0, stream>>>(
        bufB, w2, b2, bufA, B, 12000, 6000, 64);

    // prep (bufB prep region free after conv2)
    vq_prep_kernel<<<8, 256, 0, stream>>>(cbs, cc, cbf);
    wprep_kernel<<<1, 128, 0, stream>>>(wq, wfrag);
    zero_cnt_kernel<<<1, 64, 0, stream>>>(cnt);

    // conv3: (B,64,6000) -> (B,64,2000)  CO_T=16
    conv_wave_kernel<64, 3, 16, 1><<<dim3(32, 1, B), 256, 0, stream>>>(
        bufA, w3, b3, bufB, B, 6000, 2000, 64);
    // conv4: (B,64,2000) -> (B,128,2000)  split-bf16 MFMA
    conv4_mfma_kernel<<<dim3(16, B), 256, 0, stream>>>(bufB, wfrag, bq, bufA);

    // VQ: split-bf16 MFMA + flag, then exact fp32 rescore (conv4 recompute)
    vq_mfma_kernel<<<dim3(16, 2, B), 256, 0, stream>>>(bufA, cbf, cc, out, cnt, list);
    vq_rescore_kernel<<<256, 256, 0, stream>>>(bufB, wq, bq, cbs, cc, cnt, list, out);
}

// Round 9
// 1621.538 us; speedup vs baseline: 1.2317x; 1.2317x over previous
//
#include <hip/hip_runtime.h>
#include <hip/hip_bf16.h>
#include <cstddef>

// ---------------------------------------------------------------------------
// EncoderModule: 5x causal conv1d (K=7) + ELU, then 2x VQ argmin (1024 codes, D=64)
// B=64, L=48000, strides 2,2,2,3,1; channels 1->16->32->64->64->128
// Output: int32 indices, shape (2, 64, 2000)
//
// conv0-2: fp32 VALU (conv_wave). conv3/conv4: 6-term split-bf16 MFMA
// (w=w0+w1+w2, h=h0+h1+h2, pairs i+j<=2 -> fp32-class error ~1e-5).
// VQ: split-bf16 MFMA scores; gap < 0.2 -> flag; rescore v2 stages the h3
// patch in LDS (parallel loads) and recomputes z + all 1024 scores in fp32.
// ---------------------------------------------------------------------------

using bf16x8 = __attribute__((ext_vector_type(8))) short;
using f32x4  = __attribute__((ext_vector_type(4))) float;

static __device__ __forceinline__ short f2bf(float f) {
    __hip_bfloat16 h = __float2bfloat16(f);   // RNE
    union { __hip_bfloat16 h; short s; } u; u.h = h;
    return u.s;
}
static __device__ __forceinline__ float bf2f(short s) {
    union { unsigned u; float f; } v;
    v.u = ((unsigned)(unsigned short)s) << 16;
    return v.f;
}
static __device__ __forceinline__ void split3(float v, short& s0, short& s1, short& s2) {
    s0 = f2bf(v);  float r1 = v  - bf2f(s0);   // exact subtraction
    s1 = f2bf(r1); float r2 = r1 - bf2f(s1);   // exact
    s2 = f2bf(r2);                             // residual ~2^-27 |v|
}

// ---------------- conv_wave (verified): convs 0-2 ---------------------------
template<int CIN, int S, int CO_T, int TT>
__global__ __launch_bounds__(256) void conv_wave_kernel(
    const float* __restrict__ x, const float* __restrict__ w,
    const float* __restrict__ bias, float* __restrict__ y,
    int B, int Lin, int Lout, int Cout)
{
    constexpr int NT   = 64 * TT;
    constexpr int XLEN = (NT - 1) * S + 7;
    __shared__ float xs[CIN][XLEN];

    int tb  = blockIdx.x;
    int cbk = blockIdx.y;
    int b   = blockIdx.z;
    int t0  = tb * NT;
    int tid  = threadIdx.x;
    int lane = tid & 63;
    int wv   = __builtin_amdgcn_readfirstlane(tid >> 6);

    const float* xb = x + (size_t)b * CIN * Lin;
    int g0 = t0 * S - 6;
    for (int i = tid; i < CIN * XLEN; i += 256) {
        int ci = i / XLEN, xo = i % XLEN;
        int gx = g0 + xo;
        xs[ci][xo] = (gx >= 0 && gx < Lin) ? xb[(size_t)ci * Lin + gx] : 0.0f;
    }
    __syncthreads();

    int co0 = cbk * (4 * CO_T) + wv * CO_T;
    const float* wbase = w + (size_t)co0 * CIN * 7;

    float acc[CO_T][TT];
    #pragma unroll
    for (int c = 0; c < CO_T; ++c)
        #pragma unroll
        for (int u = 0; u < TT; ++u) acc[c][u] = 0.0f;

    for (int ci = 0; ci < CIN; ++ci) {
        float xw[TT][7];
        #pragma unroll
        for (int u = 0; u < TT; ++u)
            #pragma unroll
            for (int k = 0; k < 7; ++k)
                xw[u][k] = xs[ci][(lane + 64 * u) * S + k];
        #pragma unroll
        for (int c = 0; c < CO_T; ++c) {
            const float* wp = wbase + (size_t)c * CIN * 7 + ci * 7;  // s_load
            #pragma unroll
            for (int k = 0; k < 7; ++k) {
                float wk = wp[k];
                #pragma unroll
                for (int u = 0; u < TT; ++u)
                    acc[c][u] = fmaf(wk, xw[u][k], acc[c][u]);
            }
        }
    }

    #pragma unroll
    for (int u = 0; u < TT; ++u) {
        int t = t0 + lane + 64 * u;
        if (t < Lout) {
            #pragma unroll
            for (int c = 0; c < CO_T; ++c) {
                float v = acc[c][u] + bias[co0 + c];
                y[((size_t)b * Cout + co0 + c) * Lout + t] = v > 0.0f ? v : expm1f(v);
            }
        }
    }
}

// ---------------- weight prep: 3-level bf16 A-fragments ---------------------
// A element for 16x16x32: (m = mt*16 + (lane&15), k_e = kc*32 + (lane>>4)*8 + j)
// frag addr: ((((mt*KC+kc)*7+k)*3+lvl)*512 + lane*8)  shorts
template<int CIN, int COUT>
__global__ void wprep_kernel(const float* __restrict__ w, short* __restrict__ frag)
{
    constexpr int KC = CIN / 32;
    int co = threadIdx.x;
    if (co >= COUT) return;
    int mt = co >> 4, nc = co & 15;
    for (int kc = 0; kc < KC; ++kc)
        for (int k = 0; k < 7; ++k)
            #pragma unroll
            for (int lh = 0; lh < 4; ++lh) {
                bf16x8 p0, p1, p2;
                #pragma unroll
                for (int j = 0; j < 8; ++j) {
                    int ci = kc * 32 + lh * 8 + j;
                    float f = w[(size_t)co * CIN * 7 + ci * 7 + k];
                    short a, bb, c; split3(f, a, bb, c);
                    p0[j] = a; p1[j] = bb; p2[j] = c;
                }
                size_t base = ((size_t)(mt * KC + kc) * 7 + k) * 3;
                int off = (lh * 16 + nc) * 8;
                *(bf16x8*)(frag + (base + 0) * 512 + off) = p0;
                *(bf16x8*)(frag + (base + 1) * 512 + off) = p1;
                *(bf16x8*)(frag + (base + 2) * 512 + off) = p2;
            }
}

// ---------------- conv via 6-term split-bf16 MFMA (convs 3,4) ---------------
template<int S, int CIN, int COUT, int NTL>
__global__ __launch_bounds__(256) void conv_mfma_kernel(
    const float* __restrict__ hin, const short* __restrict__ wfrag,
    const float* __restrict__ bias, float* __restrict__ yout,
    int Lin, int Lout)
{
    constexpr int KC   = CIN / 32;
    constexpr int MT   = COUT / 16;
    constexpr int NT   = NTL * 64;
    constexpr int ROWS = (NT - 1) * S + 7;
    __shared__ short hl0[ROWS * 64];   // 3 planes, XOR-swizzled 128B rows
    __shared__ short hl1[ROWS * 64];
    __shared__ short hl2[ROWS * 64];

    int nb = blockIdx.x, b = blockIdx.y;
    int t0 = nb * NT;
    int tid = threadIdx.x, lane = tid & 63, wv = tid >> 6;

    const float* hb = hin + (size_t)b * CIN * Lin;
    for (int e = tid; e < CIN * ROWS; e += 256) {
        int ci = e / ROWS, rr = e % ROWS;
        int t = t0 * S - 6 + rr;
        float v = (t >= 0 && t < Lin) ? hb[(size_t)ci * Lin + t] : 0.0f;
        short a, bb, c; split3(v, a, bb, c);
        int byte = rr * 128 + ((ci * 2) ^ ((rr & 7) << 4));
        *(short*)((char*)hl0 + byte) = a;
        *(short*)((char*)hl1 + byte) = bb;
        *(short*)((char*)hl2 + byte) = c;
    }
    __syncthreads();

    f32x4 acc[NTL][MT];
    #pragma unroll
    for (int n = 0; n < NTL; ++n)
        #pragma unroll
        for (int m = 0; m < MT; ++m) acc[n][m] = (f32x4){0.f, 0.f, 0.f, 0.f};

    int ncol = lane & 15, nq = lane >> 4;

    for (int k = 0; k < 7; ++k) {
        #pragma unroll
        for (int kc = 0; kc < KC; ++kc) {
            int colb = (kc * 32 + nq * 8) * 2;
            bf16x8 B0[NTL], B1[NTL], B2[NTL];
            #pragma unroll
            for (int ntl = 0; ntl < NTL; ++ntl) {
                int r = S * ((wv * NTL + ntl) * 16 + ncol) + k;
                int byte = r * 128 + (colb ^ ((r & 7) << 4));
                B0[ntl] = *(const bf16x8*)((const char*)hl0 + byte);
                B1[ntl] = *(const bf16x8*)((const char*)hl1 + byte);
                B2[ntl] = *(const bf16x8*)((const char*)hl2 + byte);
            }
            #pragma unroll
            for (int m = 0; m < MT; ++m) {
                size_t base = ((size_t)(m * KC + kc) * 7 + k) * 3;
                bf16x8 a0 = *(const bf16x8*)(wfrag + (base + 0) * 512 + lane * 8);
                bf16x8 a1 = *(const bf16x8*)(wfrag + (base + 1) * 512 + lane * 8);
                bf16x8 a2 = *(const bf16x8*)(wfrag + (base + 2) * 512 + lane * 8);
                #pragma unroll
                for (int ntl = 0; ntl < NTL; ++ntl) {
                    f32x4 a = acc[ntl][m];
                    a = __builtin_amdgcn_mfma_f32_16x16x32_bf16(a0, B0[ntl], a, 0, 0, 0);
                    a = __builtin_amdgcn_mfma_f32_16x16x32_bf16(a1, B0[ntl], a, 0, 0, 0);
                    a = __builtin_amdgcn_mfma_f32_16x16x32_bf16(a2, B0[ntl], a, 0, 0, 0);
                    a = __builtin_amdgcn_mfma_f32_16x16x32_bf16(a0, B1[ntl], a, 0, 0, 0);
                    a = __builtin_amdgcn_mfma_f32_16x16x32_bf16(a1, B1[ntl], a, 0, 0, 0);
                    a = __builtin_amdgcn_mfma_f32_16x16x32_bf16(a0, B2[ntl], a, 0, 0, 0);
                    acc[ntl][m] = a;
                }
            }
        }
    }

    #pragma unroll
    for (int ntl = 0; ntl < NTL; ++ntl) {
        int n = t0 + (wv * NTL + ntl) * 16 + ncol;
        if (n < Lout) {
            #pragma unroll
            for (int m = 0; m < MT; ++m) {
                #pragma unroll
                for (int j = 0; j < 4; ++j) {
                    int co = m * 16 + nq * 4 + j;
                    float v = acc[ntl][m][j] + bias[co];
                    v = v > 0.0f ? v : expm1f(v);
                    yout[((size_t)b * COUT + co) * Lout + n] = v;
                }
            }
        }
    }
}

// ---------------- VQ prep: cc (fp32) + codebook hi/lo bf16 B-fragments ------
__global__ __launch_bounds__(256) void vq_prep_kernel(
    const float* __restrict__ cbs, float* __restrict__ cc, short* __restrict__ cbf)
{
    int c = blockIdx.x * 256 + threadIdx.x;   // 0..2047
    if (c >= 2048) return;
    int cb = c >> 10, nl = c & 1023;
    const float* row = cbs + (size_t)c * 64;
    float v[64];
    float s = 0.f;
    #pragma unroll
    for (int i = 0; i < 16; ++i) {
        float4 q = ((const float4*)row)[i];
        v[4*i+0] = q.x; v[4*i+1] = q.y; v[4*i+2] = q.z; v[4*i+3] = q.w;
        s += q.x*q.x + q.y*q.y + q.z*q.z + q.w*q.w;
    }
    cc[c] = s;
    int nt = nl >> 4, nc = nl & 15;
    #pragma unroll
    for (int kc = 0; kc < 2; ++kc)
        #pragma unroll
        for (int lh = 0; lh < 4; ++lh) {
            bf16x8 ph, pl;
            #pragma unroll
            for (int j = 0; j < 8; ++j) {
                float f = v[kc*32 + lh*8 + j];
                short h = f2bf(f);
                ph[j] = h;
                pl[j] = f2bf(f - bf2f(h));
            }
            size_t base = ((((size_t)cb*64 + nt)*2 + kc)*2);
            *(bf16x8*)(cbf + ((base + 0)*64 + (lh*16 + nc)) * 8) = ph;
            *(bf16x8*)(cbf + ((base + 1)*64 + (lh*16 + nc)) * 8) = pl;
        }
}

__global__ void zero_cnt_kernel(int* cnt) {
    if (threadIdx.x == 0 && blockIdx.x == 0) *cnt = 0;
}

// ---------------- VQ main: split-bf16 MFMA + best/second + flag -------------
#define VQ_MARGIN 0.2f

__global__ __launch_bounds__(256) void vq_mfma_kernel(
    const float* __restrict__ z, const short* __restrict__ cbf,
    const float* __restrict__ ccg, int* __restrict__ out,
    int* __restrict__ cnt, int* __restrict__ list)
{
    __shared__ short zf[2][8*2*64*8];     // 32 KB: A-frags [hl][mt(8)][kc(2)][lane][j]
    __shared__ short cbc[8*2*2*64*8];     // 32 KB: B-frag chunk (128 codes, hi+lo)
    __shared__ float ccl[128];

    const int T = 2000;
    int mblk = blockIdx.x;   // 16 m-blocks of 128 t
    int cb   = blockIdx.y;
    int b    = blockIdx.z;
    int t0   = mblk * 128;
    int tid  = threadIdx.x;
    int lane = tid & 63;
    int wv   = tid >> 6;

    const float* zb = z + ((size_t)b*128 + (size_t)cb*64) * T;
    bool tail = (t0 + 128 > T);
    #pragma unroll
    for (int p = 0; p < 8; ++p) {
        int d    = p*8 + (tid >> 5);
        int toff = (tid & 31) * 4;
        float qa[4];
        if (!tail) {
            float4 q = *(const float4*)(zb + (size_t)d*T + t0 + toff);
            qa[0]=q.x; qa[1]=q.y; qa[2]=q.z; qa[3]=q.w;
        } else {
            #pragma unroll
            for (int u = 0; u < 4; ++u) {
                int tt = t0 + toff + u; if (tt > T-1) tt = T-1;
                qa[u] = zb[(size_t)d*T + tt];
            }
        }
        #pragma unroll
        for (int u = 0; u < 4; ++u) {
            int tl = toff + u;
            int mt = tl >> 4;
            int lw = ((d & 31) >> 3) * 16 + (tl & 15);
            int kc = d >> 5;
            int idx = (((mt*2 + kc)*64) + lw)*8 + (d & 7);
            short h = f2bf(qa[u]);
            zf[0][idx] = h;
            zf[1][idx] = f2bf(qa[u] - bf2f(h));
        }
    }
    __syncthreads();

    bf16x8 ah[2][2], al[2][2];
    #pragma unroll
    for (int mtl = 0; mtl < 2; ++mtl)
        #pragma unroll
        for (int kc = 0; kc < 2; ++kc) {
            int idx = ((((wv*2+mtl)*2 + kc)*64) + lane)*8;
            ah[mtl][kc] = *(const bf16x8*)&zf[0][idx];
            al[mtl][kc] = *(const bf16x8*)&zf[1][idx];
        }

    float best[2][4], second[2][4]; int bidx[2][4];
    #pragma unroll
    for (int m = 0; m < 2; ++m)
        #pragma unroll
        for (int j = 0; j < 4; ++j) { best[m][j] = 3.4e38f; second[m][j] = 3.4e38f; bidx[m][j] = 0; }

    const short* cbase = cbf + (size_t)cb * (64*2*2*64*8);
    const float* ccb   = ccg + cb * 1024;

    for (int ch = 0; ch < 8; ++ch) {
        __syncthreads();
        {
            const float4* src = (const float4*)(cbase + (size_t)ch * (8*2*2*64*8));
            float4* dst = (float4*)cbc;
            #pragma unroll
            for (int i = 0; i < 8; ++i) dst[tid + 256*i] = src[tid + 256*i];
            if (tid < 128) ccl[tid] = ccb[ch*128 + tid];
        }
        __syncthreads();

        for (int ntl = 0; ntl < 8; ++ntl) {
            bf16x8 b0h = *(const bf16x8*)&cbc[(((ntl*2 + 0)*2 + 0)*64 + lane)*8];
            bf16x8 b0l = *(const bf16x8*)&cbc[(((ntl*2 + 0)*2 + 1)*64 + lane)*8];
            bf16x8 b1h = *(const bf16x8*)&cbc[(((ntl*2 + 1)*2 + 0)*64 + lane)*8];
            bf16x8 b1l = *(const bf16x8*)&cbc[(((ntl*2 + 1)*2 + 1)*64 + lane)*8];
            float ccv = ccl[ntl*16 + (lane & 15)];
            int  code = ch*128 + ntl*16 + (lane & 15);
            #pragma unroll
            for (int mtl = 0; mtl < 2; ++mtl) {
                f32x4 p = {0.f,0.f,0.f,0.f}, q = {0.f,0.f,0.f,0.f};
                p = __builtin_amdgcn_mfma_f32_16x16x32_bf16(ah[mtl][0], b0h, p, 0, 0, 0);
                q = __builtin_amdgcn_mfma_f32_16x16x32_bf16(ah[mtl][1], b1h, q, 0, 0, 0);
                p = __builtin_amdgcn_mfma_f32_16x16x32_bf16(ah[mtl][0], b0l, p, 0, 0, 0);
                q = __builtin_amdgcn_mfma_f32_16x16x32_bf16(ah[mtl][1], b1l, q, 0, 0, 0);
                p = __builtin_amdgcn_mfma_f32_16x16x32_bf16(al[mtl][0], b0h, p, 0, 0, 0);
                q = __builtin_amdgcn_mfma_f32_16x16x32_bf16(al[mtl][1], b1h, q, 0, 0, 0);
                #pragma unroll
                for (int j = 0; j < 4; ++j) {
                    float s = fmaf(-2.0f, p[j] + q[j], ccv);
                    bool lt = s < best[mtl][j];
                    second[mtl][j] = fminf(second[mtl][j], fmaxf(best[mtl][j], s));
                    best[mtl][j]   = fminf(best[mtl][j], s);
                    bidx[mtl][j]   = lt ? code : bidx[mtl][j];
                }
            }
        }
    }

    #pragma unroll
    for (int m = 0; m < 2; ++m)
        #pragma unroll
        for (int j = 0; j < 4; ++j) {
            float bv = best[m][j], sv = second[m][j]; int bi = bidx[m][j];
            #pragma unroll
            for (int d = 1; d < 16; d <<= 1) {
                float ob = __shfl_xor(bv, d, 64);
                float os = __shfl_xor(sv, d, 64);
                int   oi = __shfl_xor(bi, d, 64);
                float loser = fmaxf(bv, ob);
                sv = fminf(fminf(sv, os), loser);
                bool sw = ob < bv;
                bv = fminf(bv, ob);
                bi = sw ? oi : bi;
            }
            if ((lane & 15) == 0) {
                int t = t0 + (wv*2 + m)*16 + (lane >> 4)*4 + j;
                if (t < T) {
                    out[((size_t)cb*64 + b)*T + t] = bi;
                    if (sv - bv < VQ_MARGIN) {
                        int pos = atomicAdd(cnt, 1);
                        list[pos] = (cb << 17) | (b << 11) | t;
                    }
                }
            }
        }
}

// ---------------- VQ rescore v2: LDS-staged exact fp32 ----------------------
// Per flag: lane=ci stages the 64x7 h3 patch in parallel (one round-trip),
// then lane=d computes exact fp32 conv4 from LDS broadcasts + contiguous
// per-lane w stream (L2-resident), then exact 1024-code scan.
__global__ __launch_bounds__(256) void vq_rescore_kernel(
    const float* __restrict__ h3, const float* __restrict__ wq,
    const float* __restrict__ bq, const float* __restrict__ cbs,
    const float* __restrict__ ccg, const int* __restrict__ cnt,
    const int* __restrict__ list, int* __restrict__ out)
{
    const int T = 2000;
    __shared__ float hp[4][448];
    int tid = threadIdx.x, lane = tid & 63, wv = tid >> 6;
    int gw = blockIdx.x * 4 + wv;
    int nw = gridDim.x * 4;
    int count = *cnt;

    for (int i = gw; i < count; i += nw) {
        int e = list[i];
        int cb = e >> 17, b = (e >> 11) & 63, t = e & 2047;

        // parallel patch stage: lane = ci
        const float* hrow = h3 + ((size_t)b * 64 + lane) * T;
        #pragma unroll
        for (int kk = 0; kk < 7; ++kk) {
            int tt = t - 6 + kk;
            hp[wv][lane * 7 + kk] = (tt >= 0) ? hrow[tt] : 0.0f;
        }
        // wave-local LDS write->read: compiler inserts lgkmcnt waits (same array)

        // exact fp32 conv4 for dim d = cb*64 + lane
        int d = cb * 64 + lane;
        const float4* wp = (const float4*)(wq + (size_t)d * 448);
        const float*  hv = hp[wv];
        float a0 = 0.f, a1 = 0.f, a2 = 0.f, a3 = 0.f;
        #pragma unroll 8
        for (int q = 0; q < 112; ++q) {
            float4 w4 = wp[q];
            float4 h4 = *(const float4*)(hv + 4 * q);
            a0 = fmaf(w4.x, h4.x, a0);
            a1 = fmaf(w4.y, h4.y, a1);
            a2 = fmaf(w4.z, h4.z, a2);
            a3 = fmaf(w4.w, h4.w, a3);
        }
        float zd = (a0 + a1) + (a2 + a3) + bq[d];
        zd = zd > 0.0f ? zd : expm1f(zd);

        // broadcast z row to all lanes
        float zr[64];
        #pragma unroll
        for (int j = 0; j < 64; ++j) zr[j] = __shfl(zd, j, 64);

        const float* cbase = cbs + (size_t)cb * 1024 * 64;
        const float* ccb   = ccg + cb * 1024;
        float bv = 3.4e38f; int bi = 0x7fffffff;
        for (int ii = 0; ii < 16; ++ii) {
            int code = ii*64 + lane;
            const float4* cp = (const float4*)(cbase + (size_t)code * 64);
            float d0 = 0.f, d1 = 0.f, d2 = 0.f, d3 = 0.f;
            #pragma unroll
            for (int q = 0; q < 16; ++q) {
                float4 cv = cp[q];
                d0 = fmaf(zr[4*q+0], cv.x, d0);
                d1 = fmaf(zr[4*q+1], cv.y, d1);
                d2 = fmaf(zr[4*q+2], cv.z, d2);
                d3 = fmaf(zr[4*q+3], cv.w, d3);
            }
            float s = fmaf(-2.0f, (d0 + d1) + (d2 + d3), ccb[code]);
            if (s < bv) { bv = s; bi = code; }
        }
        #pragma unroll
        for (int dd = 1; dd < 64; dd <<= 1) {
            float ov = __shfl_xor(bv, dd, 64);
            int   oi = __shfl_xor(bi, dd, 64);
            if (ov < bv || (ov == bv && oi < bi)) { bv = ov; bi = oi; }
        }
        if (lane == 0) out[((size_t)cb*64 + b)*T + t] = bi;
    }
}

extern "C" void kernel_launch(void* const* d_in, const int* in_sizes, int n_in,
                              void* d_out, int out_size, void* d_ws, size_t ws_size,
                              hipStream_t stream)
{
    const float* x   = (const float*)d_in[0];
    const float* w0  = (const float*)d_in[1];
    const float* b0  = (const float*)d_in[2];
    const float* w1  = (const float*)d_in[3];
    const float* b1  = (const float*)d_in[4];
    const float* w2  = (const float*)d_in[5];
    const float* b2  = (const float*)d_in[6];
    const float* w3  = (const float*)d_in[7];
    const float* b3  = (const float*)d_in[8];
    const float* wq  = (const float*)d_in[9];
    const float* bq  = (const float*)d_in[10];
    const float* cbs = (const float*)d_in[11];
    int* out = (int*)d_out;

    constexpr int B = 64;
    constexpr size_t BUF = 24576000;
    float* bufA = (float*)d_ws;
    float* bufB = bufA + BUF;
    // prep region: bufB + 16M floats (free after conv2 consumes h1; beyond
    // conv3's h3 which occupies bufB[0 .. 8.192M)).
    float* prep   = bufB + 16000000;
    short* cbf    = (short*)prep;                 // 262144 shorts (VQ B-frags)
    float* cc     = prep + 131072;                // 2048 f32
    int*   cnt    = (int*)(cc + 2048);
    int*   list   = cnt + 4;                      // up to ~266K ints
    short* wfrag4 = (short*)(prep + 400000);      // 172032 shorts (conv4)
    short* wfrag3 = (short*)(prep + 486016);      // 86016 shorts  (conv3)

    // conv0: (B,1,48000) -> (B,16,24000)
    conv_wave_kernel<1, 2, 4, 2><<<dim3(188, 1, B), 256, 0, stream>>>(
        x, w0, b0, bufA, B, 48000, 24000, 16);
    // conv1: (B,16,24000) -> (B,32,12000)
    conv_wave_kernel<16, 2, 8, 2><<<dim3(94, 1, B), 256, 0, stream>>>(
        bufA, w1, b1, bufB, B, 24000, 12000, 32);
    // conv2: (B,32,12000) -> (B,64,6000)  CO_T=16
    conv_wave_kernel<32, 2, 16, 2><<<dim3(47, 1, B), 256, 0, stream>>>(
        bufB, w2, b2, bufA, B, 12000, 6000, 64);

    // prep (bufB prep region free after conv2)
    vq_prep_kernel<<<8, 256, 0, stream>>>(cbs, cc, cbf);
    wprep_kernel<64, 64><<<1, 64, 0, stream>>>(w3, wfrag3);
    wprep_kernel<64, 128><<<1, 128, 0, stream>>>(wq, wfrag4);
    zero_cnt_kernel<<<1, 64, 0, stream>>>(cnt);

    // conv3: (B,64,6000) -> (B,64,2000)  6-term MFMA, stride 3
    conv_mfma_kernel<3, 64, 64, 1><<<dim3(32, B), 256, 0, stream>>>(
        bufA, wfrag3, b3, bufB, 6000, 2000);
    // conv4: (B,64,2000) -> (B,128,2000) 6-term MFMA, stride 1
    conv_mfma_kernel<1, 64, 128, 2><<<dim3(16, B), 256, 0, stream>>>(
        bufB, wfrag4, bq, bufA, 2000, 2000);

    // VQ: split-bf16 MFMA + flag, then LDS-staged exact fp32 rescore
    vq_mfma_kernel<<<dim3(16, 2, B), 256, 0, stream>>>(bufA, cbf, cc, out, cnt, list);
    vq_rescore_kernel<<<1024, 256, 0, stream>>>(bufB, wq, bq, cbs, cc, cnt, list, out);
}

// Round 10
// 874.511 us; speedup vs baseline: 2.2839x; 1.8542x over previous
//
#include <hip/hip_runtime.h>
#include <hip/hip_bf16.h>
#include <cstddef>

// ---------------------------------------------------------------------------
// EncoderModule: 5x causal conv1d (K=7) + ELU, then 2x VQ argmin (1024 codes, D=64)
// B=64, L=48000, strides 2,2,2,3,1; channels 1->16->32->64->64->128
// Output: int32 indices, shape (2, 64, 2000)
//
// conv0-2: fp32 VALU (conv_wave). conv3/conv4: 6-term split-bf16 MFMA.
// VQ: split-bf16 MFMA scores; gap < 0.04 -> flag (per-cb lists); rescore v3
// processes 2 same-cb flags per wave iteration, sharing w-row and codebook
// loads; exact fp32 conv4 recompute + full 1024-code scan.
// ---------------------------------------------------------------------------

using bf16x8 = __attribute__((ext_vector_type(8))) short;
using f32x4  = __attribute__((ext_vector_type(4))) float;

static __device__ __forceinline__ short f2bf(float f) {
    __hip_bfloat16 h = __float2bfloat16(f);   // RNE
    union { __hip_bfloat16 h; short s; } u; u.h = h;
    return u.s;
}
static __device__ __forceinline__ float bf2f(short s) {
    union { unsigned u; float f; } v;
    v.u = ((unsigned)(unsigned short)s) << 16;
    return v.f;
}
static __device__ __forceinline__ void split3(float v, short& s0, short& s1, short& s2) {
    s0 = f2bf(v);  float r1 = v  - bf2f(s0);
    s1 = f2bf(r1); float r2 = r1 - bf2f(s1);
    s2 = f2bf(r2);
}

// ---------------- conv_wave (verified): convs 0-2 ---------------------------
template<int CIN, int S, int CO_T, int TT>
__global__ __launch_bounds__(256) void conv_wave_kernel(
    const float* __restrict__ x, const float* __restrict__ w,
    const float* __restrict__ bias, float* __restrict__ y,
    int B, int Lin, int Lout, int Cout)
{
    constexpr int NT   = 64 * TT;
    constexpr int XLEN = (NT - 1) * S + 7;
    __shared__ float xs[CIN][XLEN];

    int tb  = blockIdx.x;
    int cbk = blockIdx.y;
    int b   = blockIdx.z;
    int t0  = tb * NT;
    int tid  = threadIdx.x;
    int lane = tid & 63;
    int wv   = __builtin_amdgcn_readfirstlane(tid >> 6);

    const float* xb = x + (size_t)b * CIN * Lin;
    int g0 = t0 * S - 6;
    for (int i = tid; i < CIN * XLEN; i += 256) {
        int ci = i / XLEN, xo = i % XLEN;
        int gx = g0 + xo;
        xs[ci][xo] = (gx >= 0 && gx < Lin) ? xb[(size_t)ci * Lin + gx] : 0.0f;
    }
    __syncthreads();

    int co0 = cbk * (4 * CO_T) + wv * CO_T;
    const float* wbase = w + (size_t)co0 * CIN * 7;

    float acc[CO_T][TT];
    #pragma unroll
    for (int c = 0; c < CO_T; ++c)
        #pragma unroll
        for (int u = 0; u < TT; ++u) acc[c][u] = 0.0f;

    for (int ci = 0; ci < CIN; ++ci) {
        float xw[TT][7];
        #pragma unroll
        for (int u = 0; u < TT; ++u)
            #pragma unroll
            for (int k = 0; k < 7; ++k)
                xw[u][k] = xs[ci][(lane + 64 * u) * S + k];
        #pragma unroll
        for (int c = 0; c < CO_T; ++c) {
            const float* wp = wbase + (size_t)c * CIN * 7 + ci * 7;  // s_load
            #pragma unroll
            for (int k = 0; k < 7; ++k) {
                float wk = wp[k];
                #pragma unroll
                for (int u = 0; u < TT; ++u)
                    acc[c][u] = fmaf(wk, xw[u][k], acc[c][u]);
            }
        }
    }

    #pragma unroll
    for (int u = 0; u < TT; ++u) {
        int t = t0 + lane + 64 * u;
        if (t < Lout) {
            #pragma unroll
            for (int c = 0; c < CO_T; ++c) {
                float v = acc[c][u] + bias[co0 + c];
                y[((size_t)b * Cout + co0 + c) * Lout + t] = v > 0.0f ? v : expm1f(v);
            }
        }
    }
}

// ---------------- weight prep: 3-level bf16 A-fragments ---------------------
template<int CIN, int COUT>
__global__ void wprep_kernel(const float* __restrict__ w, short* __restrict__ frag)
{
    constexpr int KC = CIN / 32;
    int co = threadIdx.x;
    if (co >= COUT) return;
    int mt = co >> 4, nc = co & 15;
    for (int kc = 0; kc < KC; ++kc)
        for (int k = 0; k < 7; ++k)
            #pragma unroll
            for (int lh = 0; lh < 4; ++lh) {
                bf16x8 p0, p1, p2;
                #pragma unroll
                for (int j = 0; j < 8; ++j) {
                    int ci = kc * 32 + lh * 8 + j;
                    float f = w[(size_t)co * CIN * 7 + ci * 7 + k];
                    short a, bb, c; split3(f, a, bb, c);
                    p0[j] = a; p1[j] = bb; p2[j] = c;
                }
                size_t base = ((size_t)(mt * KC + kc) * 7 + k) * 3;
                int off = (lh * 16 + nc) * 8;
                *(bf16x8*)(frag + (base + 0) * 512 + off) = p0;
                *(bf16x8*)(frag + (base + 1) * 512 + off) = p1;
                *(bf16x8*)(frag + (base + 2) * 512 + off) = p2;
            }
}

// ---------------- conv via 6-term split-bf16 MFMA (convs 3,4) ---------------
template<int S, int CIN, int COUT, int NTL>
__global__ __launch_bounds__(256) void conv_mfma_kernel(
    const float* __restrict__ hin, const short* __restrict__ wfrag,
    const float* __restrict__ bias, float* __restrict__ yout,
    int Lin, int Lout)
{
    constexpr int KC   = CIN / 32;
    constexpr int MT   = COUT / 16;
    constexpr int NT   = NTL * 64;
    constexpr int ROWS = (NT - 1) * S + 7;
    __shared__ short hl0[ROWS * 64];
    __shared__ short hl1[ROWS * 64];
    __shared__ short hl2[ROWS * 64];

    int nb = blockIdx.x, b = blockIdx.y;
    int t0 = nb * NT;
    int tid = threadIdx.x, lane = tid & 63, wv = tid >> 6;

    const float* hb = hin + (size_t)b * CIN * Lin;
    for (int e = tid; e < CIN * ROWS; e += 256) {
        int ci = e / ROWS, rr = e % ROWS;
        int t = t0 * S - 6 + rr;
        float v = (t >= 0 && t < Lin) ? hb[(size_t)ci * Lin + t] : 0.0f;
        short a, bb, c; split3(v, a, bb, c);
        int byte = rr * 128 + ((ci * 2) ^ ((rr & 7) << 4));
        *(short*)((char*)hl0 + byte) = a;
        *(short*)((char*)hl1 + byte) = bb;
        *(short*)((char*)hl2 + byte) = c;
    }
    __syncthreads();

    f32x4 acc[NTL][MT];
    #pragma unroll
    for (int n = 0; n < NTL; ++n)
        #pragma unroll
        for (int m = 0; m < MT; ++m) acc[n][m] = (f32x4){0.f, 0.f, 0.f, 0.f};

    int ncol = lane & 15, nq = lane >> 4;

    for (int k = 0; k < 7; ++k) {
        #pragma unroll
        for (int kc = 0; kc < KC; ++kc) {
            int colb = (kc * 32 + nq * 8) * 2;
            bf16x8 B0[NTL], B1[NTL], B2[NTL];
            #pragma unroll
            for (int ntl = 0; ntl < NTL; ++ntl) {
                int r = S * ((wv * NTL + ntl) * 16 + ncol) + k;
                int byte = r * 128 + (colb ^ ((r & 7) << 4));
                B0[ntl] = *(const bf16x8*)((const char*)hl0 + byte);
                B1[ntl] = *(const bf16x8*)((const char*)hl1 + byte);
                B2[ntl] = *(const bf16x8*)((const char*)hl2 + byte);
            }
            #pragma unroll
            for (int m = 0; m < MT; ++m) {
                size_t base = ((size_t)(m * KC + kc) * 7 + k) * 3;
                bf16x8 a0 = *(const bf16x8*)(wfrag + (base + 0) * 512 + lane * 8);
                bf16x8 a1 = *(const bf16x8*)(wfrag + (base + 1) * 512 + lane * 8);
                bf16x8 a2 = *(const bf16x8*)(wfrag + (base + 2) * 512 + lane * 8);
                #pragma unroll
                for (int ntl = 0; ntl < NTL; ++ntl) {
                    f32x4 a = acc[ntl][m];
                    a = __builtin_amdgcn_mfma_f32_16x16x32_bf16(a0, B0[ntl], a, 0, 0, 0);
                    a = __builtin_amdgcn_mfma_f32_16x16x32_bf16(a1, B0[ntl], a, 0, 0, 0);
                    a = __builtin_amdgcn_mfma_f32_16x16x32_bf16(a2, B0[ntl], a, 0, 0, 0);
                    a = __builtin_amdgcn_mfma_f32_16x16x32_bf16(a0, B1[ntl], a, 0, 0, 0);
                    a = __builtin_amdgcn_mfma_f32_16x16x32_bf16(a1, B1[ntl], a, 0, 0, 0);
                    a = __builtin_amdgcn_mfma_f32_16x16x32_bf16(a0, B2[ntl], a, 0, 0, 0);
                    acc[ntl][m] = a;
                }
            }
        }
    }

    #pragma unroll
    for (int ntl = 0; ntl < NTL; ++ntl) {
        int n = t0 + (wv * NTL + ntl) * 16 + ncol;
        if (n < Lout) {
            #pragma unroll
            for (int m = 0; m < MT; ++m) {
                #pragma unroll
                for (int j = 0; j < 4; ++j) {
                    int co = m * 16 + nq * 4 + j;
                    float v = acc[ntl][m][j] + bias[co];
                    v = v > 0.0f ? v : expm1f(v);
                    yout[((size_t)b * COUT + co) * Lout + n] = v;
                }
            }
        }
    }
}

// ---------------- VQ prep: cc (fp32) + codebook hi/lo bf16 B-fragments ------
__global__ __launch_bounds__(256) void vq_prep_kernel(
    const float* __restrict__ cbs, float* __restrict__ cc, short* __restrict__ cbf)
{
    int c = blockIdx.x * 256 + threadIdx.x;   // 0..2047
    if (c >= 2048) return;
    int cb = c >> 10, nl = c & 1023;
    const float* row = cbs + (size_t)c * 64;
    float v[64];
    float s = 0.f;
    #pragma unroll
    for (int i = 0; i < 16; ++i) {
        float4 q = ((const float4*)row)[i];
        v[4*i+0] = q.x; v[4*i+1] = q.y; v[4*i+2] = q.z; v[4*i+3] = q.w;
        s += q.x*q.x + q.y*q.y + q.z*q.z + q.w*q.w;
    }
    cc[c] = s;
    int nt = nl >> 4, nc = nl & 15;
    #pragma unroll
    for (int kc = 0; kc < 2; ++kc)
        #pragma unroll
        for (int lh = 0; lh < 4; ++lh) {
            bf16x8 ph, pl;
            #pragma unroll
            for (int j = 0; j < 8; ++j) {
                float f = v[kc*32 + lh*8 + j];
                short h = f2bf(f);
                ph[j] = h;
                pl[j] = f2bf(f - bf2f(h));
            }
            size_t base = ((((size_t)cb*64 + nt)*2 + kc)*2);
            *(bf16x8*)(cbf + ((base + 0)*64 + (lh*16 + nc)) * 8) = ph;
            *(bf16x8*)(cbf + ((base + 1)*64 + (lh*16 + nc)) * 8) = pl;
        }
}

__global__ void zero_cnt_kernel(int* cnt) {
    if (threadIdx.x == 0 && blockIdx.x == 0) { cnt[0] = 0; cnt[1] = 0; }
}

// ---------------- VQ main: split-bf16 MFMA + best/second + flag -------------
#define VQ_MARGIN 0.04f

__global__ __launch_bounds__(256) void vq_mfma_kernel(
    const float* __restrict__ z, const short* __restrict__ cbf,
    const float* __restrict__ ccg, int* __restrict__ out,
    int* __restrict__ cnt, int* __restrict__ list0, int* __restrict__ list1)
{
    __shared__ short zf[2][8*2*64*8];
    __shared__ short cbc[8*2*2*64*8];
    __shared__ float ccl[128];

    const int T = 2000;
    int mblk = blockIdx.x;
    int cb   = blockIdx.y;
    int b    = blockIdx.z;
    int t0   = mblk * 128;
    int tid  = threadIdx.x;
    int lane = tid & 63;
    int wv   = tid >> 6;
    int* list = cb ? list1 : list0;

    const float* zb = z + ((size_t)b*128 + (size_t)cb*64) * T;
    bool tail = (t0 + 128 > T);
    #pragma unroll
    for (int p = 0; p < 8; ++p) {
        int d    = p*8 + (tid >> 5);
        int toff = (tid & 31) * 4;
        float qa[4];
        if (!tail) {
            float4 q = *(const float4*)(zb + (size_t)d*T + t0 + toff);
            qa[0]=q.x; qa[1]=q.y; qa[2]=q.z; qa[3]=q.w;
        } else {
            #pragma unroll
            for (int u = 0; u < 4; ++u) {
                int tt = t0 + toff + u; if (tt > T-1) tt = T-1;
                qa[u] = zb[(size_t)d*T + tt];
            }
        }
        #pragma unroll
        for (int u = 0; u < 4; ++u) {
            int tl = toff + u;
            int mt = tl >> 4;
            int lw = ((d & 31) >> 3) * 16 + (tl & 15);
            int kc = d >> 5;
            int idx = (((mt*2 + kc)*64) + lw)*8 + (d & 7);
            short h = f2bf(qa[u]);
            zf[0][idx] = h;
            zf[1][idx] = f2bf(qa[u] - bf2f(h));
        }
    }
    __syncthreads();

    bf16x8 ah[2][2], al[2][2];
    #pragma unroll
    for (int mtl = 0; mtl < 2; ++mtl)
        #pragma unroll
        for (int kc = 0; kc < 2; ++kc) {
            int idx = ((((wv*2+mtl)*2 + kc)*64) + lane)*8;
            ah[mtl][kc] = *(const bf16x8*)&zf[0][idx];
            al[mtl][kc] = *(const bf16x8*)&zf[1][idx];
        }

    float best[2][4], second[2][4]; int bidx[2][4];
    #pragma unroll
    for (int m = 0; m < 2; ++m)
        #pragma unroll
        for (int j = 0; j < 4; ++j) { best[m][j] = 3.4e38f; second[m][j] = 3.4e38f; bidx[m][j] = 0; }

    const short* cbase = cbf + (size_t)cb * (64*2*2*64*8);
    const float* ccb   = ccg + cb * 1024;

    for (int ch = 0; ch < 8; ++ch) {
        __syncthreads();
        {
            const float4* src = (const float4*)(cbase + (size_t)ch * (8*2*2*64*8));
            float4* dst = (float4*)cbc;
            #pragma unroll
            for (int i = 0; i < 8; ++i) dst[tid + 256*i] = src[tid + 256*i];
            if (tid < 128) ccl[tid] = ccb[ch*128 + tid];
        }
        __syncthreads();

        for (int ntl = 0; ntl < 8; ++ntl) {
            bf16x8 b0h = *(const bf16x8*)&cbc[(((ntl*2 + 0)*2 + 0)*64 + lane)*8];
            bf16x8 b0l = *(const bf16x8*)&cbc[(((ntl*2 + 0)*2 + 1)*64 + lane)*8];
            bf16x8 b1h = *(const bf16x8*)&cbc[(((ntl*2 + 1)*2 + 0)*64 + lane)*8];
            bf16x8 b1l = *(const bf16x8*)&cbc[(((ntl*2 + 1)*2 + 1)*64 + lane)*8];
            float ccv = ccl[ntl*16 + (lane & 15)];
            int  code = ch*128 + ntl*16 + (lane & 15);
            #pragma unroll
            for (int mtl = 0; mtl < 2; ++mtl) {
                f32x4 p = {0.f,0.f,0.f,0.f}, q = {0.f,0.f,0.f,0.f};
                p = __builtin_amdgcn_mfma_f32_16x16x32_bf16(ah[mtl][0], b0h, p, 0, 0, 0);
                q = __builtin_amdgcn_mfma_f32_16x16x32_bf16(ah[mtl][1], b1h, q, 0, 0, 0);
                p = __builtin_amdgcn_mfma_f32_16x16x32_bf16(ah[mtl][0], b0l, p, 0, 0, 0);
                q = __builtin_amdgcn_mfma_f32_16x16x32_bf16(ah[mtl][1], b1l, q, 0, 0, 0);
                p = __builtin_amdgcn_mfma_f32_16x16x32_bf16(al[mtl][0], b0h, p, 0, 0, 0);
                q = __builtin_amdgcn_mfma_f32_16x16x32_bf16(al[mtl][1], b1h, q, 0, 0, 0);
                #pragma unroll
                for (int j = 0; j < 4; ++j) {
                    float s = fmaf(-2.0f, p[j] + q[j], ccv);
                    bool lt = s < best[mtl][j];
                    second[mtl][j] = fminf(second[mtl][j], fmaxf(best[mtl][j], s));
                    best[mtl][j]   = fminf(best[mtl][j], s);
                    bidx[mtl][j]   = lt ? code : bidx[mtl][j];
                }
            }
        }
    }

    #pragma unroll
    for (int m = 0; m < 2; ++m)
        #pragma unroll
        for (int j = 0; j < 4; ++j) {
            float bv = best[m][j], sv = second[m][j]; int bi = bidx[m][j];
            #pragma unroll
            for (int d = 1; d < 16; d <<= 1) {
                float ob = __shfl_xor(bv, d, 64);
                float os = __shfl_xor(sv, d, 64);
                int   oi = __shfl_xor(bi, d, 64);
                float loser = fmaxf(bv, ob);
                sv = fminf(fminf(sv, os), loser);
                bool sw = ob < bv;
                bv = fminf(bv, ob);
                bi = sw ? oi : bi;
            }
            if ((lane & 15) == 0) {
                int t = t0 + (wv*2 + m)*16 + (lane >> 4)*4 + j;
                if (t < T) {
                    out[((size_t)cb*64 + b)*T + t] = bi;
                    if (sv - bv < VQ_MARGIN) {
                        int pos = atomicAdd(&cnt[cb], 1);
                        list[pos] = (b << 11) | t;
                    }
                }
            }
        }
}

// ---------------- VQ rescore v3: paired same-cb flags, shared loads ---------
// blockIdx.y = cb. Each wave handles 2 flags/iter: w-row stream and codebook
// row loads are issued once and feed both flags. z-rows broadcast via LDS.
__global__ __launch_bounds__(256) void vq_rescore_kernel(
    const float* __restrict__ h3, const float* __restrict__ wq,
    const float* __restrict__ bq, const float* __restrict__ cbs,
    const float* __restrict__ ccg, const int* __restrict__ cnt,
    const int* __restrict__ list0, const int* __restrict__ list1,
    int* __restrict__ out)
{
    const int T = 2000;
    __shared__ float hp[4][2][448];
    __shared__ float zsh[4][2][64];
    int tid = threadIdx.x, lane = tid & 63, wv = tid >> 6;
    int cb = blockIdx.y;
    const int* list = cb ? list1 : list0;
    int count = cnt[cb];
    int gw = blockIdx.x * 4 + wv, nw = gridDim.x * 4;

    const float* cbase = cbs + (size_t)cb * 1024 * 64;
    const float* ccb   = ccg + cb * 1024;
    int d = cb * 64 + lane;
    const float4* wp = (const float4*)(wq + (size_t)d * 448);
    float bqd = bq[d];

    for (int i0 = gw * 2; i0 < count; i0 += nw * 2) {
        int e0 = list[i0];
        int e1 = (i0 + 1 < count) ? list[i0 + 1] : e0;
        int b0 = e0 >> 11, t0 = e0 & 2047;
        int b1 = e1 >> 11, t1 = e1 & 2047;

        // stage both 64x7 h3 patches (lane = ci)
        const float* hrow0 = h3 + ((size_t)b0 * 64 + lane) * T;
        const float* hrow1 = h3 + ((size_t)b1 * 64 + lane) * T;
        #pragma unroll
        for (int kk = 0; kk < 7; ++kk) {
            int a0 = t0 - 6 + kk, a1 = t1 - 6 + kk;
            hp[wv][0][lane * 7 + kk] = (a0 >= 0) ? hrow0[a0] : 0.0f;
            hp[wv][1][lane * 7 + kk] = (a1 >= 0) ? hrow1[a1] : 0.0f;
        }

        // exact fp32 conv4 for dim d (w stream shared across both flags)
        float p00=0.f,p01=0.f,p02=0.f,p03=0.f, p10=0.f,p11=0.f,p12=0.f,p13=0.f;
        #pragma unroll 8
        for (int q = 0; q < 112; ++q) {
            float4 w4 = wp[q];
            float4 h0 = *(const float4*)&hp[wv][0][4 * q];
            float4 h1 = *(const float4*)&hp[wv][1][4 * q];
            p00 = fmaf(w4.x, h0.x, p00); p01 = fmaf(w4.y, h0.y, p01);
            p02 = fmaf(w4.z, h0.z, p02); p03 = fmaf(w4.w, h0.w, p03);
            p10 = fmaf(w4.x, h1.x, p10); p11 = fmaf(w4.y, h1.y, p11);
            p12 = fmaf(w4.z, h1.z, p12); p13 = fmaf(w4.w, h1.w, p13);
        }
        float z0 = (p00 + p01) + (p02 + p03) + bqd; z0 = z0 > 0.f ? z0 : expm1f(z0);
        float z1 = (p10 + p11) + (p12 + p13) + bqd; z1 = z1 > 0.f ? z1 : expm1f(z1);
        zsh[wv][0][lane] = z0;
        zsh[wv][1][lane] = z1;

        // full exact scan; codebook row loads shared across both flags
        float bv0 = 3.4e38f, bv1 = 3.4e38f; int bi0 = 0, bi1 = 0;
        for (int ii = 0; ii < 16; ++ii) {
            int code = ii * 64 + lane;
            const float4* cp = (const float4*)(cbase + (size_t)code * 64);
            float d00=0.f,d01=0.f,d02=0.f,d03=0.f, d10=0.f,d11=0.f,d12=0.f,d13=0.f;
            #pragma unroll
            for (int q = 0; q < 16; ++q) {
                float4 cv = cp[q];
                float4 za = *(const float4*)&zsh[wv][0][4 * q];   // uniform broadcast
                float4 zc = *(const float4*)&zsh[wv][1][4 * q];
                d00 = fmaf(za.x, cv.x, d00); d01 = fmaf(za.y, cv.y, d01);
                d02 = fmaf(za.z, cv.z, d02); d03 = fmaf(za.w, cv.w, d03);
                d10 = fmaf(zc.x, cv.x, d10); d11 = fmaf(zc.y, cv.y, d11);
                d12 = fmaf(zc.z, cv.z, d12); d13 = fmaf(zc.w, cv.w, d13);
            }
            float cc0 = ccb[code];
            float s0 = fmaf(-2.0f, (d00 + d01) + (d02 + d03), cc0);
            float s1 = fmaf(-2.0f, (d10 + d11) + (d12 + d13), cc0);
            if (s0 < bv0) { bv0 = s0; bi0 = code; }
            if (s1 < bv1) { bv1 = s1; bi1 = code; }
        }
        #pragma unroll
        for (int dd = 1; dd < 64; dd <<= 1) {
            float ov0 = __shfl_xor(bv0, dd, 64); int oi0 = __shfl_xor(bi0, dd, 64);
            if (ov0 < bv0 || (ov0 == bv0 && oi0 < bi0)) { bv0 = ov0; bi0 = oi0; }
            float ov1 = __shfl_xor(bv1, dd, 64); int oi1 = __shfl_xor(bi1, dd, 64);
            if (ov1 < bv1 || (ov1 == bv1 && oi1 < bi1)) { bv1 = ov1; bi1 = oi1; }
        }
        if (lane == 0) {
            out[((size_t)cb * 64 + b0) * T + t0] = bi0;
            out[((size_t)cb * 64 + b1) * T + t1] = bi1;
        }
    }
}

extern "C" void kernel_launch(void* const* d_in, const int* in_sizes, int n_in,
                              void* d_out, int out_size, void* d_ws, size_t ws_size,
                              hipStream_t stream)
{
    const float* x   = (const float*)d_in[0];
    const float* w0  = (const float*)d_in[1];
    const float* b0  = (const float*)d_in[2];
    const float* w1  = (const float*)d_in[3];
    const float* b1  = (const float*)d_in[4];
    const float* w2  = (const float*)d_in[5];
    const float* b2  = (const float*)d_in[6];
    const float* w3  = (const float*)d_in[7];
    const float* b3  = (const float*)d_in[8];
    const float* wq  = (const float*)d_in[9];
    const float* bq  = (const float*)d_in[10];
    const float* cbs = (const float*)d_in[11];
    int* out = (int*)d_out;

    constexpr int B = 64;
    constexpr size_t BUF = 24576000;
    float* bufA = (float*)d_ws;
    float* bufB = bufA + BUF;
    // prep region: bufB + 16M floats (free after conv2; beyond conv3's h3).
    float* prep   = bufB + 16000000;
    short* cbf    = (short*)prep;                 // [0, 131072) floats
    float* cc     = prep + 131072;                // 2048 f32
    int*   cnt    = (int*)(cc + 2048);            // 2 ints
    int*   list0  = (int*)(prep + 200000);        // 150000 ints
    int*   list1  = (int*)(prep + 360000);        // 150000 ints
    short* wfrag4 = (short*)(prep + 550000);      // 172032 shorts
    short* wfrag3 = (short*)(prep + 650000);      // 86016 shorts

    // conv0: (B,1,48000) -> (B,16,24000)
    conv_wave_kernel<1, 2, 4, 2><<<dim3(188, 1, B), 256, 0, stream>>>(
        x, w0, b0, bufA, B, 48000, 24000, 16);
    // conv1: (B,16,24000) -> (B,32,12000)
    conv_wave_kernel<16, 2, 8, 2><<<dim3(94, 1, B), 256, 0, stream>>>(
        bufA, w1, b1, bufB, B, 24000, 12000, 32);
    // conv2: (B,32,12000) -> (B,64,6000)
    conv_wave_kernel<32, 2, 16, 2><<<dim3(47, 1, B), 256, 0, stream>>>(
        bufB, w2, b2, bufA, B, 12000, 6000, 64);

    // prep (bufB prep region free after conv2)
    vq_prep_kernel<<<8, 256, 0, stream>>>(cbs, cc, cbf);
    wprep_kernel<64, 64><<<1, 64, 0, stream>>>(w3, wfrag3);
    wprep_kernel<64, 128><<<1, 128, 0, stream>>>(wq, wfrag4);
    zero_cnt_kernel<<<1, 64, 0, stream>>>(cnt);

    // conv3: (B,64,6000) -> (B,64,2000)  6-term MFMA, stride 3
    conv_mfma_kernel<3, 64, 64, 1><<<dim3(32, B), 256, 0, stream>>>(
        bufA, wfrag3, b3, bufB, 6000, 2000);
    // conv4: (B,64,2000) -> (B,128,2000) 6-term MFMA, stride 1
    conv_mfma_kernel<1, 64, 128, 2><<<dim3(16, B), 256, 0, stream>>>(
        bufB, wfrag4, bq, bufA, 2000, 2000);

    // VQ: split-bf16 MFMA + per-cb flag lists, then paired exact rescore
    vq_mfma_kernel<<<dim3(16, 2, B), 256, 0, stream>>>(bufA, cbf, cc, out, cnt, list0, list1);
    vq_rescore_kernel<<<dim3(512, 2), 256, 0, stream>>>(bufB, wq, bq, cbs, cc, cnt, list0, list1, out);
}